// Round 1
// baseline (456.954 us; speedup 1.0000x reference)
//
#include <hip/hip_runtime.h>
#include <hip/hip_bf16.h>

constexpr int N    = 8192;
constexpr int FIN  = 512;
constexpr int FOUT = 64;
constexpr int NSPLIT = 8;            // j-split across blocks -> 1024 blocks, co-resident
constexpr int JCHUNK = N / NSPLIT;   // 1024 j per block
constexpr int NSLICE = 4;            // internal slices per block
constexpr int JS     = JCHUNK / NSLICE;  // 256 j per LDS staging round
constexpr int LROW   = JS + 8;       // LDS B row pitch in bf16 (264 shorts)
constexpr int MWORDS = N / 32;       // 256 packed mask words per adj row

typedef __attribute__((ext_vector_type(8))) short short8;
typedef __attribute__((ext_vector_type(4))) float f32x4;

union BF2U { unsigned int u; __hip_bfloat162 h; };

// ---------------------------------------------------------------------------
// Kernel 0 (NEW, R11): adj -> bitmask pack with FILL-LIKE streaming access.
// Each wave owns one full adj row (32 KB) and streams it contiguously:
// 8192 waves = 2048 blocks, 32 waves/CU. Replaces k2's 65K concurrent
// 1KB-burst/32KB-stride reads (the hypothesized DRAM-thrash) with 8192
// sequential row streams — the same pattern the 6.6 TB/s fills use.
// Bit layout identical to k2's old Ml packing: pmask[i*256+w] bit b
// <=> adj[i][32w+b] != 0.
// ---------------------------------------------------------------------------
__global__ __launch_bounds__(256) void k0_pack(
    const int* __restrict__ adj, unsigned int* __restrict__ pmask)
{
    const int wid  = (blockIdx.x << 2) + (threadIdx.x >> 6);   // row index, 0..8191
    const int lane = threadIdx.x & 63;
    const int* rowp = adj + (size_t)wid * N;
    unsigned int* outp = pmask + (size_t)wid * MWORDS;

    #pragma unroll 4
    for (int t = 0; t < 32; ++t) {                 // 32 x 1KB contiguous chunks
        const int4 av = *(const int4*)(rowp + (t << 8) + (lane << 2));
        unsigned int v = (av.x != 0 ? 1u : 0u) | (av.y != 0 ? 2u : 0u) |
                         (av.z != 0 ? 4u : 0u) | (av.w != 0 ? 8u : 0u);
        // tree-combine: lane l%8==0 ends with 32 bits covering cols 4l..4l+31
        v |= (unsigned int)__shfl_xor((int)v, 1, 64) << 4;
        v |= (unsigned int)__shfl_xor((int)v, 2, 64) << 8;
        v |= (unsigned int)__shfl_xor((int)v, 4, 64) << 16;
        if ((lane & 7) == 0)
            outp[(t << 3) + (lane >> 3)] = v;      // 8 lanes -> 32B contiguous
    }
}

// ---------------------------------------------------------------------------
// Kernel 1: h = input @ W (fp32), fused epilogue:
//   E1=exp(s1), F1=exp(0.2 s1), E2=exp(s2), F2=exp(0.2 s2)  (exp-free k2)
//   + bf16 h^T write (B-operand feed for MFMA).   (unchanged from R7)
// ---------------------------------------------------------------------------
__global__ __launch_bounds__(256) void k1_proj(
    const float* __restrict__ input, const float* __restrict__ W,
    const float* __restrict__ a, __hip_bfloat16* __restrict__ hbT,
    float* __restrict__ E1, float* __restrict__ F1,
    float* __restrict__ E2, float* __restrict__ F2)
{
    __shared__ __hip_bfloat16 tile[8][64];
    const int tid  = threadIdx.x;
    const int col  = tid & 63;
    const int g    = tid >> 6;
    const int rbase = blockIdx.x * 8;

    float acc[2] = {0.f, 0.f};
    const float* in0 = input + (size_t)(rbase + g * 2) * FIN;

    for (int k = 0; k < FIN; k += 8) {
        float w[8];
        #pragma unroll
        for (int q = 0; q < 8; ++q) w[q] = W[(k + q) * FOUT + col];
        const float4 x0a = *(const float4*)(in0 + 0 * FIN + k);
        const float4 x0b = *(const float4*)(in0 + 0 * FIN + k + 4);
        const float4 x1a = *(const float4*)(in0 + 1 * FIN + k);
        const float4 x1b = *(const float4*)(in0 + 1 * FIN + k + 4);
        acc[0] = fmaf(x0a.w, w[3], fmaf(x0a.z, w[2], fmaf(x0a.y, w[1], fmaf(x0a.x, w[0], acc[0]))));
        acc[0] = fmaf(x0b.w, w[7], fmaf(x0b.z, w[6], fmaf(x0b.y, w[5], fmaf(x0b.x, w[4], acc[0]))));
        acc[1] = fmaf(x1a.w, w[3], fmaf(x1a.z, w[2], fmaf(x1a.y, w[1], fmaf(x1a.x, w[0], acc[1]))));
        acc[1] = fmaf(x1b.w, w[7], fmaf(x1b.z, w[6], fmaf(x1b.y, w[5], fmaf(x1b.x, w[4], acc[1]))));
    }

    const float a1c = a[col];
    const float a2c = a[FOUT + col];
    #pragma unroll
    for (int q = 0; q < 2; ++q) {
        float r1 = acc[q] * a1c;
        float r2 = acc[q] * a2c;
        #pragma unroll
        for (int off = 32; off >= 1; off >>= 1) {
            r1 += __shfl_xor(r1, off, 64);
            r2 += __shfl_xor(r2, off, 64);
        }
        if (col == 0) {
            const int i = rbase + g * 2 + q;
            E1[i] = __expf(r1);
            F1[i] = __expf(0.2f * r1);
            E2[i] = __expf(r2);
            F2[i] = __expf(0.2f * r2);
        }
        tile[g * 2 + q][col] = __float2bfloat16(acc[q]);
    }
    __syncthreads();

    if (tid < 128) {
        const int c = tid >> 1, part = tid & 1;
        unsigned short v[4];
        #pragma unroll
        for (int u = 0; u < 4; ++u) {
            __hip_bfloat16 hv = tile[part * 4 + u][c];
            v[u] = *reinterpret_cast<unsigned short*>(&hv);
        }
        *(ushort4*)((unsigned short*)hbT + (size_t)c * N + rbase + part * 4) =
            make_ushort4(v[0], v[1], v[2], v[3]);
    }
}

// ---------------------------------------------------------------------------
// Kernel 2: attention + PV via MFMA. R11 change: adj staging (64KB/slice of
// raw int32 at 32KB row stride) replaced by packed-bitmask staging
// (2KB/slice from the 8.4MB L3-resident pmask). Compute path untouched;
// mask bit semantics identical. Slice rotation dropped (its motivating
// hypothesis is moot with adj reads gone from this kernel).
// grid (128 r-tiles, 8 s-chunks) = 1024 blocks, ~38 KB LDS, 4 blocks/CU.
// ---------------------------------------------------------------------------
__global__ __launch_bounds__(256, 4) void k2_attn(
    const unsigned int* __restrict__ pmask,
    const float* __restrict__ E1, const float* __restrict__ F1,
    const float* __restrict__ E2, const float* __restrict__ F2,
    const unsigned short* __restrict__ hbT,
    float* __restrict__ pAcc, float* __restrict__ pZ)
{
    __shared__ unsigned short Bl[64 * LROW];   // 33.8 KB, padded rows
    __shared__ unsigned int   Ml[64 * 9];      // bitmask: 8 u32/row + 1 pad word
    __shared__ float          E2l[JS];         // 1 KB
    __shared__ float          F2l[JS];         // 1 KB

    const int r   = blockIdx.x;
    const int s   = blockIdx.y;
    const int tid = threadIdx.x;
    const int w     = tid >> 6;
    const int lane  = tid & 63;
    const int row16 = lane & 15;
    const int quad  = lane >> 4;

    const int iloc = w * 16 + row16;
    const int i    = r * 64 + iloc;
    const float E1i = E1[i];
    const float F1i = F1[i];

    short8 ones;
    #pragma unroll
    for (int q = 0; q < 8; ++q) ones[q] = (short)0x3F80;   // bf16 1.0

    f32x4 acc0 = {0.f, 0.f, 0.f, 0.f};
    f32x4 acc1 = {0.f, 0.f, 0.f, 0.f};
    f32x4 acc2 = {0.f, 0.f, 0.f, 0.f};
    f32x4 acc3 = {0.f, 0.f, 0.f, 0.f};
    f32x4 accz = {0.f, 0.f, 0.f, 0.f};

    for (int sl = 0; sl < NSLICE; ++sl) {
        const int jbeg = s * JCHUNK + sl * JS;

        // ---- stage packed masks: 64 rows x 8 words = 2 KB ----
        {
            const int rloc = tid >> 2;              // 0..63
            const int wp   = (tid & 3) << 1;        // 0,2,4,6
            const uint2 mv = *(const uint2*)(
                pmask + (size_t)(r * 64 + rloc) * MWORDS + (jbeg >> 5) + wp);
            Ml[rloc * 9 + wp]     = mv.x;
            Ml[rloc * 9 + wp + 1] = mv.y;
        }
        // ---- stage B: 64 feature rows x 256 bf16 ----
        #pragma unroll
        for (int rr = 0; rr < 8; ++rr) {
            const int seg = rr * 256 + tid;        // [0, 2048) 16B-segments
            const int f = seg >> 5, o = seg & 31;
            const short8 v = *(const short8*)((const short*)hbT + (size_t)f * N + jbeg + o * 8);
            *(short8*)(&Bl[f * LROW + o * 8]) = v;
        }
        // ---- stage E2/F2 slices (JS == 256 == blockDim) ----
        E2l[tid] = E2[jbeg + tid];
        F2l[tid] = F2[jbeg + tid];
        __syncthreads();

        #pragma unroll
        for (int it = 0; it < JS / 32; ++it) {     // 8 iterations
            const int jj = it * 32 + quad * 8;

            const unsigned int mword = Ml[iloc * 9 + it];
            const unsigned int mbyte = (mword >> (8 * quad)) & 0xffu;

            const float4 eA = *(const float4*)(&E2l[jj]);
            const float4 eB = *(const float4*)(&E2l[jj + 4]);
            const float4 fA = *(const float4*)(&F2l[jj]);
            const float4 fB = *(const float4*)(&F2l[jj + 4]);

            const short8 b0 = *(const short8*)(&Bl[(row16 +  0) * LROW + jj]);
            const short8 b1 = *(const short8*)(&Bl[(row16 + 16) * LROW + jj]);
            const short8 b2 = *(const short8*)(&Bl[(row16 + 32) * LROW + jj]);
            const short8 b3 = *(const short8*)(&Bl[(row16 + 48) * LROW + jj]);

            float e2v[8], f2v[8];
            e2v[0] = eA.x; e2v[1] = eA.y; e2v[2] = eA.z; e2v[3] = eA.w;
            e2v[4] = eB.x; e2v[5] = eB.y; e2v[6] = eB.z; e2v[7] = eB.w;
            f2v[0] = fA.x; f2v[1] = fA.y; f2v[2] = fA.z; f2v[3] = fA.w;
            f2v[4] = fB.x; f2v[5] = fB.y; f2v[6] = fB.z; f2v[7] = fB.w;

            float pv[8];
            #pragma unroll
            for (int j = 0; j < 8; ++j) {
                // exp(leakyrelu(s1+s2)) == max(E1*E2, F1*F2) exactly
                float p = fmaxf(E1i * e2v[j], F1i * f2v[j]);
                pv[j] = ((mbyte >> j) & 1u) ? p : 0.f;
            }

            short8 afrag;
            #pragma unroll
            for (int jp = 0; jp < 4; ++jp) {       // packed bf16 cvt (RNE)
                BF2U cv;
                cv.h = __float22bfloat162_rn(make_float2(pv[2 * jp], pv[2 * jp + 1]));
                afrag[2 * jp]     = (short)(cv.u & 0xffffu);
                afrag[2 * jp + 1] = (short)(cv.u >> 16);
            }

            acc0 = __builtin_amdgcn_mfma_f32_16x16x32_bf16(afrag, b0, acc0, 0, 0, 0);
            acc1 = __builtin_amdgcn_mfma_f32_16x16x32_bf16(afrag, b1, acc1, 0, 0, 0);
            acc2 = __builtin_amdgcn_mfma_f32_16x16x32_bf16(afrag, b2, acc2, 0, 0, 0);
            acc3 = __builtin_amdgcn_mfma_f32_16x16x32_bf16(afrag, b3, acc3, 0, 0, 0);
            accz = __builtin_amdgcn_mfma_f32_16x16x32_bf16(afrag, ones, accz, 0, 0, 0);
        }
        __syncthreads();   // LDS reuse safety before next slice restage
    }

    // z epilogue: D row m = quad*4+reg (duplicated across the 16 col-lanes)
    if (row16 == 0) {
        #pragma unroll
        for (int reg = 0; reg < 4; ++reg)
            pZ[(size_t)s * N + r * 64 + w * 16 + quad * 4 + reg] = accz[reg];
    }

    // out-tile: C/D layout col=lane&15, row=quad*4+reg
    float* outp = pAcc + ((size_t)s * N + (size_t)r * 64 + w * 16) * FOUT;
    #pragma unroll
    for (int reg = 0; reg < 4; ++reg) {
        const int row = quad * 4 + reg;
        outp[row * FOUT + ( 0 + row16)] = acc0[reg];
        outp[row * FOUT + (16 + row16)] = acc1[reg];
        outp[row * FOUT + (32 + row16)] = acc2[reg];
        outp[row * FOUT + (48 + row16)] = acc3[reg];
    }
}

// ---------------------------------------------------------------------------
// Kernel 3: out[i][f] = sum_s pAcc[s][i][f] / sum_s pZ[s][i]
// ---------------------------------------------------------------------------
__global__ __launch_bounds__(256) void k3_combine(
    const float* __restrict__ pAcc, const float* __restrict__ pZ,
    float* __restrict__ out)
{
    const int idx = blockIdx.x * 256 + threadIdx.x;
    const int i = idx >> 6;
    float num = 0.f, den = 0.f;
    #pragma unroll
    for (int s = 0; s < NSPLIT; ++s) {
        num += pAcc[(size_t)s * N * FOUT + idx];
        den += pZ[(size_t)s * N + i];
    }
    out[idx] = num / den;
}

// ---------------------------------------------------------------------------
extern "C" void kernel_launch(void* const* d_in, const int* in_sizes, int n_in,
                              void* d_out, int out_size, void* d_ws, size_t ws_size,
                              hipStream_t stream)
{
    const float* input = (const float*)d_in[0];
    const int*   adj   = (const int*)d_in[1];
    const float* W     = (const float*)d_in[2];
    const float* a     = (const float*)d_in[3];
    float* out = (float*)d_out;

    char* ws = (char*)d_ws;
    __hip_bfloat16* hbT = (__hip_bfloat16*)ws;               // 1 MB
    float* E1   = (float*)(ws + (size_t)FOUT * N * 2);       // 32 KB
    float* F1   = E1 + N;                                    // 32 KB
    float* E2   = F1 + N;                                    // 32 KB
    float* F2   = E2 + N;                                    // 32 KB
    float* pZ   = F2 + N;                                    // NSPLIT*N*4 = 256 KB
    float* pAcc = pZ + (size_t)NSPLIT * N;                   // 16.8 MB
    unsigned int* pmask = (unsigned int*)(pAcc + (size_t)NSPLIT * N * FOUT); // 8.4 MB

    // adj bit-pack: fill-like streaming (8192 row-streams, 32 waves/CU)
    k0_pack<<<N / 4, 256, 0, stream>>>(adj, pmask);

    k1_proj<<<N / 8, 256, 0, stream>>>(input, W, a, hbT, E1, F1, E2, F2);

    dim3 g2(N / 64, NSPLIT);
    k2_attn<<<g2, 256, 0, stream>>>(pmask, E1, F1, E2, F2,
                                    (const unsigned short*)hbT, pAcc, pZ);

    k3_combine<<<(N * FOUT) / 256, 256, 0, stream>>>(pAcc, pZ, out);
}

// Round 3
// 451.702 us; speedup vs baseline: 1.0116x; 1.0116x over previous
//
#include <hip/hip_runtime.h>
#include <hip/hip_bf16.h>

constexpr int N    = 8192;
constexpr int FIN  = 512;
constexpr int FOUT = 64;
constexpr int NSPLIT = 8;            // j-split across blocks -> (128,8) grid
constexpr int JCHUNK = N / NSPLIT;   // 1024 j per block
constexpr int NSLICE = 8;            // R13: 8 slices of 128 j (was 4x256)
constexpr int JS     = JCHUNK / NSLICE;  // 128 j per staging round

typedef __attribute__((ext_vector_type(8))) short short8;
typedef __attribute__((ext_vector_type(4))) float f32x4;

union BF2U { unsigned int u; __hip_bfloat162 h; };

// ---------------------------------------------------------------------------
// Kernel 1: h = input @ W (fp32), fused epilogue:
//   E1=exp(s1), F1=exp(0.2 s1), E2=exp(s2), F2=exp(0.2 s2)  (exp-free k2)
//   + bf16 h^T write (B-operand feed for MFMA).   (unchanged, proven)
// ---------------------------------------------------------------------------
__global__ __launch_bounds__(256) void k1_proj(
    const float* __restrict__ input, const float* __restrict__ W,
    const float* __restrict__ a, __hip_bfloat16* __restrict__ hbT,
    float* __restrict__ E1, float* __restrict__ F1,
    float* __restrict__ E2, float* __restrict__ F2)
{
    __shared__ __hip_bfloat16 tile[8][64];
    const int tid  = threadIdx.x;
    const int col  = tid & 63;
    const int g    = tid >> 6;
    const int rbase = blockIdx.x * 8;

    float acc[2] = {0.f, 0.f};
    const float* in0 = input + (size_t)(rbase + g * 2) * FIN;

    for (int k = 0; k < FIN; k += 8) {
        float w[8];
        #pragma unroll
        for (int q = 0; q < 8; ++q) w[q] = W[(k + q) * FOUT + col];
        const float4 x0a = *(const float4*)(in0 + 0 * FIN + k);
        const float4 x0b = *(const float4*)(in0 + 0 * FIN + k + 4);
        const float4 x1a = *(const float4*)(in0 + 1 * FIN + k);
        const float4 x1b = *(const float4*)(in0 + 1 * FIN + k + 4);
        acc[0] = fmaf(x0a.w, w[3], fmaf(x0a.z, w[2], fmaf(x0a.y, w[1], fmaf(x0a.x, w[0], acc[0]))));
        acc[0] = fmaf(x0b.w, w[7], fmaf(x0b.z, w[6], fmaf(x0b.y, w[5], fmaf(x0b.x, w[4], acc[0]))));
        acc[1] = fmaf(x1a.w, w[3], fmaf(x1a.z, w[2], fmaf(x1a.y, w[1], fmaf(x1a.x, w[0], acc[1]))));
        acc[1] = fmaf(x1b.w, w[7], fmaf(x1b.z, w[6], fmaf(x1b.y, w[5], fmaf(x1b.x, w[4], acc[1]))));
    }

    const float a1c = a[col];
    const float a2c = a[FOUT + col];
    #pragma unroll
    for (int q = 0; q < 2; ++q) {
        float r1 = acc[q] * a1c;
        float r2 = acc[q] * a2c;
        #pragma unroll
        for (int off = 32; off >= 1; off >>= 1) {
            r1 += __shfl_xor(r1, off, 64);
            r2 += __shfl_xor(r2, off, 64);
        }
        if (col == 0) {
            const int i = rbase + g * 2 + q;
            E1[i] = __expf(r1);
            F1[i] = __expf(0.2f * r1);
            E2[i] = __expf(r2);
            F2[i] = __expf(0.2f * r2);
        }
        tile[g * 2 + q][col] = __float2bfloat16(acc[q]);
    }
    __syncthreads();

    if (tid < 128) {
        const int c = tid >> 1, part = tid & 1;
        unsigned short v[4];
        #pragma unroll
        for (int u = 0; u < 4; ++u) {
            __hip_bfloat16 hv = tile[part * 4 + u][c];
            v[u] = *reinterpret_cast<unsigned short*>(&hv);
        }
        *(ushort4*)((unsigned short*)hbT + (size_t)c * N + rbase + part * 4) =
            make_ushort4(v[0], v[1], v[2], v[3]);
    }
}

// ---------------------------------------------------------------------------
// Kernel 2 (R13): attention + PV via MFMA.
//  - masks: per-thread-window adj loads (each thread loads its own row's
//    8-col windows, packs 1 u32/slice in registers) — Ml LDS + shfl pack gone.
//  - T14 pipeline: issue next slice's adj/B/EF loads BEFORE the MFMA block,
//    pack + ds_write AFTER -> HBM streams through the barriers; 1 barrier/slice.
//  - B tile [64][128] bf16 double-buffered with T2 XOR swizzle (byte ^= (f&7)<<4)
//    -> 34.8 KB LDS, 4 blocks/CU kept.
// Compute arithmetic identical to R10 (same MFMAs, same bf16 cvt, same mask
// semantics) -> absmax unchanged.
// ---------------------------------------------------------------------------
__global__ __launch_bounds__(256, 4) void k2_attn(
    const int* __restrict__ adj,
    const float* __restrict__ E1, const float* __restrict__ F1,
    const float* __restrict__ E2, const float* __restrict__ F2,
    const unsigned short* __restrict__ hbT,
    float* __restrict__ pAcc, float* __restrict__ pZ)
{
    __shared__ unsigned short Bl[2][64 * 128];   // 32 KB, XOR-swizzled rows
    __shared__ float          EFl[2][2 * JS];    // 2 KB: [0..127]=E2, [128..255]=F2

    const int r   = blockIdx.x;
    const int s   = blockIdx.y;
    const int tid = threadIdx.x;
    const int w     = tid >> 6;
    const int lane  = tid & 63;
    const int row16 = lane & 15;
    const int quad  = lane >> 4;

    const int iloc = w * 16 + row16;
    const int i    = r * 64 + iloc;
    const float E1i = E1[i];
    const float F1i = F1[i];
    const int jbase = s * JCHUNK;
    // this thread's own adj row, offset to its quad's 8-col windows
    const int* __restrict__ adjW = adj + (size_t)i * N + jbase + quad * 8;

    short8 ones;
    #pragma unroll
    for (int q = 0; q < 8; ++q) ones[q] = (short)0x3F80;   // bf16 1.0

    // prefetch registers (in flight across the compute phase)
    int4   pa[8];
    short8 pb[4];
    float  pef;

    auto issueLoads = [&](int sl) {
        #pragma unroll
        for (int it = 0; it < 4; ++it) {
            const int coff = (sl * 4 + it) * 32;           // window base (ints)
            pa[it * 2]     = *(const int4*)(adjW + coff);
            pa[it * 2 + 1] = *(const int4*)(adjW + coff + 4);
        }
        const int jb = jbase + sl * JS;
        #pragma unroll
        for (int rr = 0; rr < 4; ++rr) {
            const int seg = rr * 256 + tid;                // [0,1024) 16B-segments
            const int f = seg >> 4, o = seg & 15;
            pb[rr] = *(const short8*)(hbT + (size_t)f * N + jb + o * 8);
        }
        pef = (tid < JS) ? E2[jb + tid] : F2[jb + tid - JS];
    };
    auto packMask = [&]() -> unsigned int {
        unsigned int m = 0;
        #pragma unroll
        for (int it = 0; it < 4; ++it) {
            const int4 a = pa[it * 2], b = pa[it * 2 + 1];
            const unsigned int byte =
                (a.x != 0 ?   1u : 0u) | (a.y != 0 ?   2u : 0u) |
                (a.z != 0 ?   4u : 0u) | (a.w != 0 ?   8u : 0u) |
                (b.x != 0 ?  16u : 0u) | (b.y != 0 ?  32u : 0u) |
                (b.z != 0 ?  64u : 0u) | (b.w != 0 ? 128u : 0u);
            m |= byte << (it * 8);
        }
        return m;
    };
    auto writeStage = [&](int buf) {
        char* bbase = (char*)&Bl[buf][0];
        #pragma unroll
        for (int rr = 0; rr < 4; ++rr) {
            const int seg = rr * 256 + tid;
            const int f = seg >> 4, o = seg & 15;
            *(short8*)(bbase + f * 256 + ((o * 16) ^ ((f & 7) << 4))) = pb[rr];
        }
        EFl[buf][tid] = pef;
    };

    // prologue: slice 0
    issueLoads(0);
    unsigned int maskCur = packMask();
    writeStage(0);
    __syncthreads();

    f32x4 acc0 = {0.f, 0.f, 0.f, 0.f};
    f32x4 acc1 = {0.f, 0.f, 0.f, 0.f};
    f32x4 acc2 = {0.f, 0.f, 0.f, 0.f};
    f32x4 acc3 = {0.f, 0.f, 0.f, 0.f};
    f32x4 accz = {0.f, 0.f, 0.f, 0.f};

    const int sw = (row16 & 7) << 4;   // read-side XOR (matches write swizzle)

    for (int sl = 0; sl < NSLICE; ++sl) {
        const int cur = sl & 1;
        if (sl < NSLICE - 1) issueLoads(sl + 1);   // in flight during MFMAs

        #pragma unroll
        for (int it = 0; it < JS / 32; ++it) {     // 4 iterations
            const int jj = it * 32 + quad * 8;
            const unsigned int mbyte = (maskCur >> (it * 8)) & 0xffu;

            const float4 eA = *(const float4*)(&EFl[cur][jj]);
            const float4 eB = *(const float4*)(&EFl[cur][jj + 4]);
            const float4 fA = *(const float4*)(&EFl[cur][JS + jj]);
            const float4 fB = *(const float4*)(&EFl[cur][JS + jj + 4]);

            const int cb = it * 64 + quad * 16;    // col byte offset in row
            const char* bbase = (const char*)&Bl[cur][0];
            const short8 b0 = *(const short8*)(bbase + (row16 +  0) * 256 + (cb ^ sw));
            const short8 b1 = *(const short8*)(bbase + (row16 + 16) * 256 + (cb ^ sw));
            const short8 b2 = *(const short8*)(bbase + (row16 + 32) * 256 + (cb ^ sw));
            const short8 b3 = *(const short8*)(bbase + (row16 + 48) * 256 + (cb ^ sw));

            float e2v[8], f2v[8];
            e2v[0] = eA.x; e2v[1] = eA.y; e2v[2] = eA.z; e2v[3] = eA.w;
            e2v[4] = eB.x; e2v[5] = eB.y; e2v[6] = eB.z; e2v[7] = eB.w;
            f2v[0] = fA.x; f2v[1] = fA.y; f2v[2] = fA.z; f2v[3] = fA.w;
            f2v[4] = fB.x; f2v[5] = fB.y; f2v[6] = fB.z; f2v[7] = fB.w;

            float pv[8];
            #pragma unroll
            for (int j = 0; j < 8; ++j) {
                // exp(leakyrelu(s1+s2)) == max(E1*E2, F1*F2) exactly
                float p = fmaxf(E1i * e2v[j], F1i * f2v[j]);
                pv[j] = ((mbyte >> j) & 1u) ? p : 0.f;
            }

            short8 afrag;
            #pragma unroll
            for (int jp = 0; jp < 4; ++jp) {       // packed bf16 cvt (RNE)
                BF2U cv;
                cv.h = __float22bfloat162_rn(make_float2(pv[2 * jp], pv[2 * jp + 1]));
                afrag[2 * jp]     = (short)(cv.u & 0xffffu);
                afrag[2 * jp + 1] = (short)(cv.u >> 16);
            }

            acc0 = __builtin_amdgcn_mfma_f32_16x16x32_bf16(afrag, b0, acc0, 0, 0, 0);
            acc1 = __builtin_amdgcn_mfma_f32_16x16x32_bf16(afrag, b1, acc1, 0, 0, 0);
            acc2 = __builtin_amdgcn_mfma_f32_16x16x32_bf16(afrag, b2, acc2, 0, 0, 0);
            acc3 = __builtin_amdgcn_mfma_f32_16x16x32_bf16(afrag, b3, acc3, 0, 0, 0);
            accz = __builtin_amdgcn_mfma_f32_16x16x32_bf16(afrag, ones, accz, 0, 0, 0);
        }

        if (sl < NSLICE - 1) {
            maskCur = packMask();      // vmcnt on pa satisfied during MFMAs
            writeStage(cur ^ 1);       // other buffer: no readers this slice
        }
        __syncthreads();               // single barrier per slice
    }

    // z epilogue: D row m = quad*4+reg (duplicated across the 16 col-lanes)
    if (row16 == 0) {
        #pragma unroll
        for (int reg = 0; reg < 4; ++reg)
            pZ[(size_t)s * N + r * 64 + w * 16 + quad * 4 + reg] = accz[reg];
    }

    // out-tile: C/D layout col=lane&15, row=quad*4+reg
    float* outp = pAcc + ((size_t)s * N + (size_t)r * 64 + w * 16) * FOUT;
    #pragma unroll
    for (int reg = 0; reg < 4; ++reg) {
        const int row = quad * 4 + reg;
        outp[row * FOUT + ( 0 + row16)] = acc0[reg];
        outp[row * FOUT + (16 + row16)] = acc1[reg];
        outp[row * FOUT + (32 + row16)] = acc2[reg];
        outp[row * FOUT + (48 + row16)] = acc3[reg];
    }
}

// ---------------------------------------------------------------------------
// Kernel 3: out[i][f] = sum_s pAcc[s][i][f] / sum_s pZ[s][i]
// ---------------------------------------------------------------------------
__global__ __launch_bounds__(256) void k3_combine(
    const float* __restrict__ pAcc, const float* __restrict__ pZ,
    float* __restrict__ out)
{
    const int idx = blockIdx.x * 256 + threadIdx.x;
    const int i = idx >> 6;
    float num = 0.f, den = 0.f;
    #pragma unroll
    for (int s = 0; s < NSPLIT; ++s) {
        num += pAcc[(size_t)s * N * FOUT + idx];
        den += pZ[(size_t)s * N + i];
    }
    out[idx] = num / den;
}

// ---------------------------------------------------------------------------
extern "C" void kernel_launch(void* const* d_in, const int* in_sizes, int n_in,
                              void* d_out, int out_size, void* d_ws, size_t ws_size,
                              hipStream_t stream)
{
    const float* input = (const float*)d_in[0];
    const int*   adj   = (const int*)d_in[1];
    const float* W     = (const float*)d_in[2];
    const float* a     = (const float*)d_in[3];
    float* out = (float*)d_out;

    char* ws = (char*)d_ws;
    __hip_bfloat16* hbT = (__hip_bfloat16*)ws;               // 1 MB
    float* E1   = (float*)(ws + (size_t)FOUT * N * 2);       // 32 KB
    float* F1   = E1 + N;                                    // 32 KB
    float* E2   = F1 + N;                                    // 32 KB
    float* F2   = E2 + N;                                    // 32 KB
    float* pZ   = F2 + N;                                    // NSPLIT*N*4 = 256 KB
    float* pAcc = pZ + (size_t)NSPLIT * N;                   // 16.8 MB

    k1_proj<<<N / 8, 256, 0, stream>>>(input, W, a, hbT, E1, F1, E2, F2);

    dim3 g2(N / 64, NSPLIT);
    k2_attn<<<g2, 256, 0, stream>>>(adj, E1, F1, E2, F2,
                                    (const unsigned short*)hbT, pAcc, pZ);

    k3_combine<<<(N * FOUT) / 256, 256, 0, stream>>>(pAcc, pZ, out);
}